// Round 14
// baseline (619.322 us; speedup 1.0000x reference)
//
#include <hip/hip_runtime.h>
#include <hip/hip_fp16.h>
#include <math.h>

#define L 64
#define FIXS 65536.0f     // 2^16 fixed-point scale; attr-sum field = 24 bits, count = 8 bits
#define WAITCNT_LGKM0 0xC07F   // vmcnt=63, expcnt=7, lgkmcnt=0

typedef _Float16 f16x8 __attribute__((ext_vector_type(8)));
typedef float f32x4 __attribute__((ext_vector_type(4)));

// f32 += f16 * f32 without explicit cvt (v_fma_mix_f32: converts f16 operand to
// f32 exactly, then f32 FMA -> bit-identical to cvt+fma, one instruction).
#define FMAMIX_LO(acc, pkh, ws) \
    asm("v_fma_mix_f32 %0, %1, %2, %0 op_sel:[0,0,0] op_sel_hi:[1,0,0]" \
        : "+v"(acc) : "v"(pkh), "v"(ws))
#define FMAMIX_HI(acc, pkh, ws) \
    asm("v_fma_mix_f32 %0, %1, %2, %0 op_sel:[1,0,0] op_sel_hi:[1,0,0]" \
        : "+v"(acc) : "v"(pkh), "v"(ws))
// d = max(a+b, 0) on packed f16 pairs (2 instructions vs add+2cmp+2sel)
#define PKADDRELU(d, a, b) \
    asm("v_pk_add_f16 %0, %1, %2\n\tv_pk_max_f16 %0, %0, 0" \
        : "=v"(d) : "v"(a), "v"(b))

// gather-loop helpers: 8-lane groups, 16B row slices.
// NOTE: macro params must NOT be named x/y/z/w (cpp substitutes into .x etc).
#define GLOAD(xw_, qv_, J) \
    xw_ = (unsigned)__shfl((int)mwv, (J) * 8 + grp); \
    qv_ = h4[(size_t)(xw_ & 0x1FFFFu) * 8 + sub];
#define FMA8(A, qv_, xw_) { \
    float wv_ = __half2float(__ushort_as_half((unsigned short)((xw_) >> 17))); \
    FMAMIX_LO(A[0], (qv_).x, wv_); FMAMIX_HI(A[1], (qv_).x, wv_); \
    FMAMIX_LO(A[2], (qv_).y, wv_); FMAMIX_HI(A[3], (qv_).y, wv_); \
    FMAMIX_LO(A[4], (qv_).z, wv_); FMAMIX_HI(A[5], (qv_).z, wv_); \
    FMAMIX_LO(A[6], (qv_).w, wv_); FMAMIX_HI(A[7], (qv_).w, wv_); }

// ---------- preprocessing ----------

__global__ void k_hist(const int* __restrict__ col, const float* __restrict__ attr,
                       unsigned* __restrict__ degcnt,
                       int* __restrict__ rank, int E) {
    int e = blockIdx.x * blockDim.x + threadIdx.x;
    if (e < E) {
        int c = col[e];
        unsigned fx = (unsigned)(int)rintf(attr[e] * FIXS);
        unsigned old = atomicAdd(&degcnt[c], (1u << 24) | fx);
        rank[e] = (int)(old >> 24);
    }
}

__global__ void k_dinv(const unsigned* __restrict__ degcnt,
                       float* __restrict__ dinv, int* __restrict__ cntI,
                       float* __restrict__ rcnt, int N) {
    int n = blockIdx.x * blockDim.x + threadIdx.x;
    if (n < N) {
        unsigned p = degcnt[n];
        unsigned cnt = p >> 24;
        float d = (float)(p & 0xFFFFFFu) * (1.0f / FIXS);
        dinv[n] = (d > 0.f) ? (1.0f / sqrtf(fmaxf(d, 1e-30f))) : 0.f;
        cntI[n] = (int)cnt;
        unsigned c = cnt ? cnt : 1u;
        rcnt[n] = 1.0f / (float)c;
    }
}

// ---------- device-wide exclusive scan of cntI -> ptr ----------

__global__ __launch_bounds__(256) void k_scan_a(const int* __restrict__ cntI,
                                                int* __restrict__ blockSums, int N) {
    __shared__ int red[4];
    int b = blockIdx.x, t = threadIdx.x;
    int base = b * 1024 + t * 4;
    int s = 0;
    #pragma unroll
    for (int i = 0; i < 4; ++i) { int idx = base + i; if (idx < N) s += cntI[idx]; }
    #pragma unroll
    for (int off = 32; off > 0; off >>= 1) s += __shfl_down(s, off);
    if ((t & 63) == 0) red[t >> 6] = s;
    __syncthreads();
    if (t == 0) blockSums[b] = red[0] + red[1] + red[2] + red[3];
}

__global__ __launch_bounds__(1024) void k_scan_b(int* __restrict__ blockSums, int B,
                                                 int* __restrict__ ptr, int N) {
    __shared__ int sh[1024];
    int t = threadIdx.x;
    sh[t] = (t < B) ? blockSums[t] : 0;
    __syncthreads();
    for (int off = 1; off < 1024; off <<= 1) {
        int v = (t >= off) ? sh[t - off] : 0;
        __syncthreads();
        sh[t] += v;
        __syncthreads();
    }
    if (t < B) blockSums[t] = (t == 0) ? 0 : sh[t - 1];   // exclusive
    if (t == B - 1) ptr[N] = sh[t];                        // total
}

__global__ __launch_bounds__(256) void k_scan_c(const int* __restrict__ cntI,
                                                const int* __restrict__ blockSums,
                                                int* __restrict__ ptr, int N) {
    __shared__ int th[256];
    int b = blockIdx.x, t = threadIdx.x;
    int base = b * 1024 + t * 4;
    int v[4]; int s = 0;
    #pragma unroll
    for (int i = 0; i < 4; ++i) {
        int idx = base + i;
        v[i] = (idx < N) ? cntI[idx] : 0;
        s += v[i];
    }
    th[t] = s;
    __syncthreads();
    for (int off = 1; off < 256; off <<= 1) {
        int xv = (t >= off) ? th[t - off] : 0;
        __syncthreads();
        th[t] += xv;
        __syncthreads();
    }
    int pre = ((t == 0) ? 0 : th[t - 1]) + blockSums[b];
    #pragma unroll
    for (int i = 0; i < 4; ++i) {
        int idx = base + i;
        if (idx < N) ptr[idx] = pre;
        pre += v[i];
    }
}

// ---------- CSR build ----------

__global__ void k_scatter(const int* __restrict__ row, const int* __restrict__ col,
                          const float* __restrict__ attr, const float* __restrict__ dinv,
                          const int* __restrict__ colptr,
                          int* __restrict__ rank,
                          unsigned* __restrict__ csrX, int E) {
    int e = blockIdx.x * blockDim.x + threadIdx.x;
    if (e < E) {
        int r = row[e], c = col[e];
        int pos = colptr[c] + rank[e];
        float nrm = dinv[r] * attr[e] * dinv[c];
        unsigned short nb = __half_as_ushort(__float2half(nrm));   // sign bit = 0
        csrX[pos] = (unsigned)r | ((unsigned)nb << 17);
        rank[e] = pos;
    }
}

// ---------- colof fill: colof[colptr[n]..colptr[n+1]) = n (contiguous runs) ----------

__global__ __launch_bounds__(256) void k_fill(const int* __restrict__ colptr,
                                              int* __restrict__ colof, int N) {
    int lane = threadIdx.x & 63;
    int wid  = (blockIdx.x * blockDim.x + threadIdx.x) >> 6;
    int nw   = (gridDim.x * blockDim.x) >> 6;
    for (int n = wid; n < N; n += nw) {
        int beg = colptr[n], end = colptr[n + 1];
        for (int p = beg + lane; p < end; p += 64) colof[p] = n;
    }
}

// ---------- encoder folding: g1 = x * (w_enc@W1) + b_enc@W1 (rank-1) ----------

__global__ void k_fold(const float* __restrict__ w_enc, const float* __restrict__ b_enc,
                       const float* __restrict__ W1,
                       float* __restrict__ we1, float* __restrict__ be1) {
    int j = threadIdx.x;
    if (j < L) {
        float a = 0.f, b = 0.f;
        for (int f = 0; f < L; ++f) {
            float wv = W1[f * L + j];
            a += w_enc[f] * wv;
            b += b_enc[f] * wv;
        }
        we1[j] = a; be1[j] = b;
    }
}

__global__ void k_encode(const float* __restrict__ x, const float* __restrict__ we1,
                         const float* __restrict__ be1, __half* __restrict__ g, int N) {
    int idx = blockIdx.x * blockDim.x + threadIdx.x;
    if (idx < N * L) {
        int n = idx >> 6, f = idx & 63;
        g[idx] = __float2half(x[n] * we1[f] + be1[f]);
    }
}

// ---------- gather-aggregate with 2-STAGE NODE PIPELINE ----------
// R13: 8-waves/SIMD occupancy bump was null -> per-wave serial chain suspect.
// Now: metadata prefetched 2 nodes ahead; the NEXT node's gathers (deg<=32,
// ~96% of nodes: whole list in 4 staged uint4/lane) are issued BEFORE the
// current node's reduce+store, so they fly during the ~150cy epilogue.
// Big nodes (deg>32) use the old synchronous PROC path. (256,5): 102-VGPR
// budget holds the +~35-VGPR staging without spill (R10 lesson).

__global__ __launch_bounds__(256, 5) void k_agg(const uint4* __restrict__ h4,
        __half* __restrict__ h_out, const float* __restrict__ bias,
        const int* __restrict__ colptr, const unsigned* __restrict__ csrX,
        const float* __restrict__ rcnt, int N) {
    int lane = threadIdx.x & 63;
    int grp  = lane >> 3;              // 8 groups of 8 lanes
    int sub  = lane & 7;               // 16B slice index within a row
    int wid  = (blockIdx.x * blockDim.x + threadIdx.x) >> 6;
    int nw   = (gridDim.x * blockDim.x) >> 6;

    float bl8[8];                      // bias for features 8*sub..8*sub+7
    #pragma unroll
    for (int i = 0; i < 8; ++i) bl8[i] = bias[8 * sub + i];

    // metadata pipeline: M0 = current node n, M1 = node n+nw
    int beg0 = 0, end0 = 0; unsigned mw0 = 0;
    int beg1 = 0, end1 = 0; unsigned mw1 = 0;
    if (wid < N) {
        beg0 = colptr[wid]; end0 = colptr[wid + 1];
        if (beg0 + lane < end0) mw0 = csrX[beg0 + lane];   // inactive: 0 -> +0
    }
    if (wid + nw < N) {
        beg1 = colptr[wid + nw]; end1 = colptr[wid + nw + 1];
        if (beg1 + lane < end1) mw1 = csrX[beg1 + lane];
    }

    // staged gathers for the CURRENT node (issued in prologue / prev iteration)
    uint4 sq0, sq1, sq2, sq3;
    unsigned sx0 = 0, sx1 = 0, sx2 = 0, sx3 = 0;
    int curSk = -1;                    // -1 => not staged (PROC path)
    {
        int m0 = end0 - beg0;
        if (wid < N && m0 <= 32) {
            curSk = (m0 + 7) >> 3;     // wave-uniform
            if (curSk > 0) { sx0 = (unsigned)__shfl((int)mw0, grp);
                             sq0 = h4[(size_t)(sx0 & 0x1FFFFu) * 8 + sub]; }
            if (curSk > 1) { sx1 = (unsigned)__shfl((int)mw0, 8 + grp);
                             sq1 = h4[(size_t)(sx1 & 0x1FFFFu) * 8 + sub]; }
            if (curSk > 2) { sx2 = (unsigned)__shfl((int)mw0, 16 + grp);
                             sq2 = h4[(size_t)(sx2 & 0x1FFFFu) * 8 + sub]; }
            if (curSk > 3) { sx3 = (unsigned)__shfl((int)mw0, 24 + grp);
                             sq3 = h4[(size_t)(sx3 & 0x1FFFFu) * 8 + sub]; }
        }
    }

    for (int n = wid; n < N; n += nw) {
        float rcv = rcnt[n];

        // (a) stage NEXT node (n+nw) from M1 (ready) BEFORE consuming current
        int nSk = -1;
        unsigned nx0 = 0, nx1 = 0, nx2 = 0, nx3 = 0;
        uint4 nq0, nq1, nq2, nq3;
        int m1 = end1 - beg1;
        if (n + nw < N && m1 <= 32) {
            nSk = (m1 + 7) >> 3;
            if (nSk > 0) { nx0 = (unsigned)__shfl((int)mw1, grp);
                           nq0 = h4[(size_t)(nx0 & 0x1FFFFu) * 8 + sub]; }
            if (nSk > 1) { nx1 = (unsigned)__shfl((int)mw1, 8 + grp);
                           nq1 = h4[(size_t)(nx1 & 0x1FFFFu) * 8 + sub]; }
            if (nSk > 2) { nx2 = (unsigned)__shfl((int)mw1, 16 + grp);
                           nq2 = h4[(size_t)(nx2 & 0x1FFFFu) * 8 + sub]; }
            if (nSk > 3) { nx3 = (unsigned)__shfl((int)mw1, 24 + grp);
                           nq3 = h4[(size_t)(nx3 & 0x1FFFFu) * 8 + sub]; }
        }

        // (b) shift metadata M1 -> (preserved) and prefetch M2 into M1
        int begp = beg1, endp = end1; unsigned mwp = mw1;
        int n2 = n + 2 * nw;
        if (n2 < N) {
            beg1 = colptr[n2]; end1 = colptr[n2 + 1];
            mw1 = (beg1 + lane < end1) ? csrX[beg1 + lane] : 0;
        } else { beg1 = 0; end1 = 0; mw1 = 0; }

        // (c) accumulate current node
        float va[8];
        #pragma unroll
        for (int i = 0; i < 8; ++i) va[i] = 0.f;

        if (curSk >= 0) {              // staged fast path (deg <= 32)
            if (curSk > 0) FMA8(va, sq0, sx0)
            if (curSk > 1) FMA8(va, sq1, sx1)
            if (curSk > 2) FMA8(va, sq2, sx2)
            if (curSk > 3) FMA8(va, sq3, sx3)
        } else {                       // big node: synchronous path
            auto PROC = [&](unsigned mwv, int mm) {
                int kmax = (mm + 7) >> 3;
                int k = 0;
                while (k < kmax) {
                    int rem = kmax - k;
                    if (rem >= 4) {
                        unsigned x0, x1, x2, x3; uint4 q0, q1, q2, q3;
                        GLOAD(x0, q0, k) GLOAD(x1, q1, k + 1)
                        GLOAD(x2, q2, k + 2) GLOAD(x3, q3, k + 3)
                        FMA8(va, q0, x0) FMA8(va, q1, x1)
                        FMA8(va, q2, x2) FMA8(va, q3, x3)
                        k += 4;
                    } else if (rem == 3) {
                        unsigned x0, x1, x2; uint4 q0, q1, q2;
                        GLOAD(x0, q0, k) GLOAD(x1, q1, k + 1) GLOAD(x2, q2, k + 2)
                        FMA8(va, q0, x0) FMA8(va, q1, x1) FMA8(va, q2, x2)
                        k += 3;
                    } else if (rem == 2) {
                        unsigned x0, x1; uint4 q0, q1;
                        GLOAD(x0, q0, k) GLOAD(x1, q1, k + 1)
                        FMA8(va, q0, x0) FMA8(va, q1, x1)
                        k += 2;
                    } else {
                        unsigned x0; uint4 q0;
                        GLOAD(x0, q0, k)
                        FMA8(va, q0, x0)
                        k += 1;
                    }
                }
            };
            int m = end0 - beg0; if (m > 64) m = 64;
            PROC(mw0, m);
            for (int base = beg0 + 64; base < end0; base += 64) {  // rare deg>64
                int mm = end0 - base; if (mm > 64) mm = 64;
                unsigned mwc = 0;
                if (lane < mm) mwc = csrX[base + lane];
                PROC(mwc, mm);
            }
        }

        // (d) reduce the 8 edge-groups; lane sub holds feats 8*sub..8*sub+7
        float s[8];
        #pragma unroll
        for (int i = 0; i < 8; ++i) {
            float v = va[i];
            v += __shfl_xor(v, 8);
            v += __shfl_xor(v, 16);
            v += __shfl_xor(v, 32);
            s[i] = v;
        }
        if (lane < 8) {                // sub == lane: features 8*lane..8*lane+7
            unsigned u[4];
            #pragma unroll
            for (int i = 0; i < 4; ++i) {
                float oa = fmaxf(s[2 * i]     * rcv + bl8[2 * i],     0.f);
                float ob = fmaxf(s[2 * i + 1] * rcv + bl8[2 * i + 1], 0.f);
                u[i] = (unsigned)__half_as_ushort(__float2half(oa))
                     | ((unsigned)__half_as_ushort(__float2half(ob)) << 16);
            }
            uint4 st; st.x = u[0]; st.y = u[1]; st.z = u[2]; st.w = u[3];
            ((uint4*)h_out)[(size_t)n * 8 + lane] = st;
        }

        // (e) rotate: current <- next
        beg0 = begp; end0 = endp; mw0 = mwp;
        curSk = nSk;
        sx0 = nx0; sx1 = nx1; sx2 = nx2; sx3 = nx3;
        sq0 = nq0; sq1 = nq1; sq2 = nq2; sq3 = nq3;
    }
}

// ---------- dense transform g = h @ W via MFMA (split-fp16 W: full f32 accuracy) ----------

__global__ __launch_bounds__(256) void k_gx(const __half* __restrict__ h,
        const float* __restrict__ W, __half* __restrict__ g, int N) {
    int lane = threadIdx.x & 63;
    int wid  = (blockIdx.x * blockDim.x + threadIdx.x) >> 6;
    int nw   = (gridDim.x * blockDim.x) >> 6;
    int r16  = lane & 15;
    int q4   = lane >> 4;

    f16x8 bh[4][2], bl[4][2];          // B frags: [col-tile][k-step]
    #pragma unroll
    for (int t = 0; t < 4; ++t)
        #pragma unroll
        for (int ks = 0; ks < 2; ++ks)
            #pragma unroll
            for (int i = 0; i < 8; ++i) {
                int k = ks * 32 + q4 * 8 + i;
                float wv = W[k * L + t * 16 + r16];
                _Float16 hi = (_Float16)wv;
                bh[t][ks][i] = hi;
                bl[t][ks][i] = (_Float16)(wv - (float)hi);
            }

    int tiles = (N + 15) >> 4;
    for (int tt = wid; tt < tiles; tt += nw) {
        int n0 = tt << 4;
        int row = n0 + r16; if (row >= N) row = N - 1;
        f16x8 a0 = *(const f16x8*)(h + (size_t)row * L + q4 * 8);
        f16x8 a1 = *(const f16x8*)(h + (size_t)row * L + 32 + q4 * 8);
        #pragma unroll
        for (int t = 0; t < 4; ++t) {
            f32x4 acc = {0.f, 0.f, 0.f, 0.f};
            acc = __builtin_amdgcn_mfma_f32_16x16x32_f16(a0, bl[t][0], acc, 0, 0, 0);
            acc = __builtin_amdgcn_mfma_f32_16x16x32_f16(a1, bl[t][1], acc, 0, 0, 0);
            acc = __builtin_amdgcn_mfma_f32_16x16x32_f16(a0, bh[t][0], acc, 0, 0, 0);
            acc = __builtin_amdgcn_mfma_f32_16x16x32_f16(a1, bh[t][1], acc, 0, 0, 0);
            #pragma unroll
            for (int r = 0; r < 4; ++r) {
                int node = n0 + q4 * 4 + r;
                if (node < N)
                    g[(size_t)node * L + t * 16 + r16] = __float2half(acc[r]);
            }
        }
    }
}

// ---------- decoder node matvecs via MFMA: U = h@W1[:64]+b1, V = h@W1[64:] ----------

__global__ __launch_bounds__(256) void k_mv2(const __half* __restrict__ h,
        const float* __restrict__ W1, const float* __restrict__ b1,
        __half* __restrict__ U, __half* __restrict__ V, int N) {
    int lane = threadIdx.x & 63;
    int wid  = (blockIdx.x * blockDim.x + threadIdx.x) >> 6;
    int nw   = (gridDim.x * blockDim.x) >> 6;
    int r16  = lane & 15;
    int q4   = lane >> 4;
    int tiles = (N + 15) >> 4;

    for (int phase = 0; phase < 2; ++phase) {
        const float* W = W1 + (size_t)phase * L * L;   // Wu rows 0..63, Wv rows 64..127
        __half* O = phase ? V : U;
        f16x8 bh[4][2], bl[4][2];
        float bv[4];
        #pragma unroll
        for (int t = 0; t < 4; ++t) {
            bv[t] = phase ? 0.f : b1[t * 16 + r16];
            #pragma unroll
            for (int ks = 0; ks < 2; ++ks)
                #pragma unroll
                for (int i = 0; i < 8; ++i) {
                    int k = ks * 32 + q4 * 8 + i;
                    float wv = W[k * L + t * 16 + r16];
                    _Float16 hi = (_Float16)wv;
                    bh[t][ks][i] = hi;
                    bl[t][ks][i] = (_Float16)(wv - (float)hi);
                }
        }
        for (int tt = wid; tt < tiles; tt += nw) {
            int n0 = tt << 4;
            int row = n0 + r16; if (row >= N) row = N - 1;
            f16x8 a0 = *(const f16x8*)(h + (size_t)row * L + q4 * 8);
            f16x8 a1 = *(const f16x8*)(h + (size_t)row * L + 32 + q4 * 8);
            #pragma unroll
            for (int t = 0; t < 4; ++t) {
                f32x4 acc = {0.f, 0.f, 0.f, 0.f};
                acc = __builtin_amdgcn_mfma_f32_16x16x32_f16(a0, bl[t][0], acc, 0, 0, 0);
                acc = __builtin_amdgcn_mfma_f32_16x16x32_f16(a1, bl[t][1], acc, 0, 0, 0);
                acc = __builtin_amdgcn_mfma_f32_16x16x32_f16(a0, bh[t][0], acc, 0, 0, 0);
                acc = __builtin_amdgcn_mfma_f32_16x16x32_f16(a1, bh[t][1], acc, 0, 0, 0);
                #pragma unroll
                for (int r = 0; r < 4; ++r) {
                    int node = n0 + q4 * 4 + r;
                    if (node < N)
                        O[(size_t)node * L + t * 16 + r16] = __float2half(acc[r] + bv[t]);
                }
            }
        }
    }
}

// ---------- decoder edge pass: EDGE-PARALLEL, 8 lanes per CSR position ----------

__global__ __launch_bounds__(256, 8) void k_edge(const __half* __restrict__ U,
        const __half* __restrict__ V, const float* __restrict__ w2,
        const float* __restrict__ b2, const unsigned* __restrict__ csrX,
        const int* __restrict__ colof, float* __restrict__ tmp, int E) {
    int sub = threadIdx.x & 7;
    float w2f[8];
    #pragma unroll
    for (int i = 0; i < 8; ++i) w2f[i] = w2[8 * sub + i];
    float b2v = b2[0];
    int tid = blockIdx.x * blockDim.x + threadIdx.x;
    int np  = (gridDim.x * blockDim.x) >> 3;
    for (int p = tid >> 3; p < E; p += np) {
        unsigned md = csrX[p];
        int r = (int)(md & 0x1FFFFu);
        int n = colof[p];
        uint4 uq = ((const uint4*)(U + (size_t)r * L))[sub];
        uint4 vq = ((const uint4*)(V + (size_t)n * L))[sub];
        float p0 = 0.f, p1 = 0.f;
        #define DOT2X(uw_, vw_, B) { unsigned t_; \
            PKADDRELU(t_, (uw_), (vw_)); \
            FMAMIX_LO(p0, t_, w2f[B]); FMAMIX_HI(p1, t_, w2f[(B) + 1]); }
        DOT2X(uq.x, vq.x, 0) DOT2X(uq.y, vq.y, 2)
        DOT2X(uq.z, vq.z, 4) DOT2X(uq.w, vq.w, 6)
        #undef DOT2X
        float pd = p0 + p1;
        pd += __shfl_xor(pd, 1);
        pd += __shfl_xor(pd, 2);
        pd += __shfl_xor(pd, 4);
        if (sub == 0) tmp[p] = pd + b2v;
    }
}

// ---------- permute CSR-ordered results back to edge order (+ softplus) ----------

__global__ void k_perm(const int* __restrict__ epos, const float* __restrict__ tmp,
                       const int* __restrict__ erow, const int* __restrict__ ecol,
                       float* __restrict__ out, int E) {
    int e = blockIdx.x * blockDim.x + threadIdx.x;
    if (e < E) {
        float val = tmp[epos[e]];
        if (erow[e] == ecol[e])
            val = fmaxf(val, 0.f) + log1pf(expf(-fabsf(val)));
        out[e] = val;
    }
}

// ---------- launch ----------

extern "C" void kernel_launch(void* const* d_in, const int* in_sizes, int n_in,
                              void* d_out, int out_size, void* d_ws, size_t ws_size,
                              hipStream_t stream) {
    const float* x     = (const float*)d_in[0];
    const float* attr  = (const float*)d_in[1];
    const float* w_enc = (const float*)d_in[2];
    const float* b_enc = (const float*)d_in[3];
    const float* c1w   = (const float*)d_in[4];
    const float* c1b   = (const float*)d_in[5];
    const float* c2w   = (const float*)d_in[6];
    const float* c2b   = (const float*)d_in[7];
    const float* dw1   = (const float*)d_in[8];
    const float* db1   = (const float*)d_in[9];
    const float* dw2   = (const float*)d_in[10];
    const float* db2   = (const float*)d_in[11];
    const int*   erow  = (const int*)d_in[12];
    const int*   ecol  = (const int*)d_in[13];
    int N = in_sizes[0];
    int E = in_sizes[1];
    float* out = (float*)d_out;

    char* w = (char*)d_ws;
    auto alloc = [&](size_t bytes) {
        char* p = w; w += (bytes + 255) & ~(size_t)255; return p;
    };
    unsigned* degcnt = (unsigned*)alloc((size_t)N * 4);  // zeroed
    size_t zbytes = (size_t)(w - (char*)d_ws);
    float* dinv   = (float*)alloc((size_t)N * 4);
    int*   cntI   = (int*)  alloc((size_t)N * 4);
    float* rcnt   = (float*)alloc((size_t)N * 4);
    int*   colptr = (int*)  alloc((size_t)(N + 1) * 4);
    int*   bsums  = (int*)  alloc(((size_t)(N + 1023) / 1024 + 1) * 4);
    float* we1    = (float*)alloc(L * 4);
    float* be1    = (float*)alloc(L * 4);
    int*   rank   = (int*)  alloc((size_t)E * 4);   // per-col rank, then abs CSR pos
    unsigned* csrX = (unsigned*)alloc((size_t)E * 4);
    int*   colof  = (int*)  alloc((size_t)E * 4);   // owning col per CSR position
    float* tmp    = (float*)alloc((size_t)E * 4);
    __half* hA    = (__half*)alloc((size_t)N * L * 2);   // fp16 h ping
    __half* hB    = (__half*)alloc((size_t)N * L * 2);   // fp16 h pong
    __half* hU    = (__half*)alloc((size_t)N * L * 2);   // decoder U; aliases g
    __half* hV    = (__half*)alloc((size_t)N * L * 2);   // decoder V (fp16)
    __half* gbuf  = hU;   // g buffer lives in hU until k_mv2 (which reads hB)
    (void)ws_size; (void)n_in; (void)out_size;

    (void)hipMemsetAsync(d_ws, 0, zbytes, stream);

    int eb = (E + 255) / 256;
    int nb = (N + 255) / 256;
    int B  = (N + 1023) / 1024;     // scan chunks
    k_hist<<<eb, 256, 0, stream>>>(ecol, attr, degcnt, rank, E);
    k_dinv<<<nb, 256, 0, stream>>>(degcnt, dinv, cntI, rcnt, N);
    k_scan_a<<<B, 256, 0, stream>>>(cntI, bsums, N);
    k_scan_b<<<1, 1024, 0, stream>>>(bsums, B, colptr, N);
    k_scan_c<<<B, 256, 0, stream>>>(cntI, bsums, colptr, N);
    k_scatter<<<eb, 256, 0, stream>>>(erow, ecol, attr, dinv, colptr, rank, csrX, E);
    k_fill<<<1024, 256, 0, stream>>>(colptr, colof, N);

    // encoder folded with conv1_0's W: g1 = x * (w_enc@W) + b_enc@W
    k_fold<<<1, 64, 0, stream>>>(w_enc, b_enc, c1w, we1, be1);
    k_encode<<<(N * L + 255) / 256, 256, 0, stream>>>(x, we1, be1, gbuf, N);

    // 6 conv layers: agg(g) -> h; then g = h @ W_next (except after the last)
    const float* Ws[6] = {c1w,             c2w,
                          c1w + L * L,     c2w + L * L,
                          c1w + 2 * L * L, c2w + 2 * L * L};
    const float* Bs[6] = {c1b,         c2b,
                          c1b + L,     c2b + L,
                          c1b + 2 * L, c2b + 2 * L};
    (void)Ws[0];   // folded into the encoder
    __half* outs[2] = {hA, hB};
    __half* hcur = nullptr;
    for (int j = 0; j < 6; ++j) {
        hcur = outs[j & 1];
        k_agg<<<2048, 256, 0, stream>>>((const uint4*)gbuf, hcur, Bs[j],
                                        colptr, csrX, rcnt, N);
        if (j < 5)
            k_gx<<<512, 256, 0, stream>>>(hcur, Ws[j + 1], gbuf, N);
    }
    // h_final in hcur (= hB). U -> hU (b1 folded), V -> hV
    k_mv2<<<512, 256, 0, stream>>>(hcur, dw1, db1, hU, hV, N);
    k_edge<<<2048, 256, 0, stream>>>(hU, hV, dw2, db2, csrX, colof, tmp, E);
    k_perm<<<eb, 256, 0, stream>>>(rank, tmp, erow, ecol, out, E);
}

// Round 15
// 564.013 us; speedup vs baseline: 1.0981x; 1.0981x over previous
//
#include <hip/hip_runtime.h>
#include <hip/hip_fp16.h>
#include <math.h>

#define L 64
#define FIXS 65536.0f     // 2^16 fixed-point scale; attr-sum field = 24 bits, count = 8 bits
#define WAITCNT_LGKM0 0xC07F   // vmcnt=63, expcnt=7, lgkmcnt=0

typedef _Float16 f16x8 __attribute__((ext_vector_type(8)));
typedef float f32x4 __attribute__((ext_vector_type(4)));

// f32 += f16 * f32 without explicit cvt (v_fma_mix_f32: converts f16 operand to
// f32 exactly, then f32 FMA -> bit-identical to cvt+fma, one instruction).
#define FMAMIX_LO(acc, pkh, ws) \
    asm("v_fma_mix_f32 %0, %1, %2, %0 op_sel:[0,0,0] op_sel_hi:[1,0,0]" \
        : "+v"(acc) : "v"(pkh), "v"(ws))
#define FMAMIX_HI(acc, pkh, ws) \
    asm("v_fma_mix_f32 %0, %1, %2, %0 op_sel:[1,0,0] op_sel_hi:[1,0,0]" \
        : "+v"(acc) : "v"(pkh), "v"(ws))
// d = max(a+b, 0) on packed f16 pairs (2 instructions vs add+2cmp+2sel)
#define PKADDRELU(d, a, b) \
    asm("v_pk_add_f16 %0, %1, %2\n\tv_pk_max_f16 %0, %0, 0" \
        : "=v"(d) : "v"(a), "v"(b))

// gather-loop helpers: 8-lane groups, 16B row slices.
// NOTE: macro params must NOT be named x/y/z/w (cpp substitutes into .x etc).
#define GLOAD(xw_, qv_, J) \
    xw_ = (unsigned)__shfl((int)mwv, (J) * 8 + grp); \
    qv_ = h4[(size_t)(xw_ & 0x1FFFFu) * 8 + sub];
#define FMA8(A, qv_, xw_) { \
    float wv_ = __half2float(__ushort_as_half((unsigned short)((xw_) >> 17))); \
    FMAMIX_LO(A[0], (qv_).x, wv_); FMAMIX_HI(A[1], (qv_).x, wv_); \
    FMAMIX_LO(A[2], (qv_).y, wv_); FMAMIX_HI(A[3], (qv_).y, wv_); \
    FMAMIX_LO(A[4], (qv_).z, wv_); FMAMIX_HI(A[5], (qv_).z, wv_); \
    FMAMIX_LO(A[6], (qv_).w, wv_); FMAMIX_HI(A[7], (qv_).w, wv_); }

// ---------- preprocessing ----------

__global__ void k_hist(const int* __restrict__ col, const float* __restrict__ attr,
                       unsigned* __restrict__ degcnt,
                       int* __restrict__ rank, int E) {
    int e = blockIdx.x * blockDim.x + threadIdx.x;
    if (e < E) {
        int c = col[e];
        unsigned fx = (unsigned)(int)rintf(attr[e] * FIXS);
        unsigned old = atomicAdd(&degcnt[c], (1u << 24) | fx);
        rank[e] = (int)(old >> 24);
    }
}

__global__ void k_dinv(const unsigned* __restrict__ degcnt,
                       float* __restrict__ dinv, int* __restrict__ cntI,
                       float* __restrict__ rcnt, int N) {
    int n = blockIdx.x * blockDim.x + threadIdx.x;
    if (n < N) {
        unsigned p = degcnt[n];
        unsigned cnt = p >> 24;
        float d = (float)(p & 0xFFFFFFu) * (1.0f / FIXS);
        dinv[n] = (d > 0.f) ? (1.0f / sqrtf(fmaxf(d, 1e-30f))) : 0.f;
        cntI[n] = (int)cnt;
        unsigned c = cnt ? cnt : 1u;
        rcnt[n] = 1.0f / (float)c;
    }
}

// ---------- device-wide exclusive scan of cntI -> ptr ----------

__global__ __launch_bounds__(256) void k_scan_a(const int* __restrict__ cntI,
                                                int* __restrict__ blockSums, int N) {
    __shared__ int red[4];
    int b = blockIdx.x, t = threadIdx.x;
    int base = b * 1024 + t * 4;
    int s = 0;
    #pragma unroll
    for (int i = 0; i < 4; ++i) { int idx = base + i; if (idx < N) s += cntI[idx]; }
    #pragma unroll
    for (int off = 32; off > 0; off >>= 1) s += __shfl_down(s, off);
    if ((t & 63) == 0) red[t >> 6] = s;
    __syncthreads();
    if (t == 0) blockSums[b] = red[0] + red[1] + red[2] + red[3];
}

__global__ __launch_bounds__(1024) void k_scan_b(int* __restrict__ blockSums, int B,
                                                 int* __restrict__ ptr, int N) {
    __shared__ int sh[1024];
    int t = threadIdx.x;
    sh[t] = (t < B) ? blockSums[t] : 0;
    __syncthreads();
    for (int off = 1; off < 1024; off <<= 1) {
        int v = (t >= off) ? sh[t - off] : 0;
        __syncthreads();
        sh[t] += v;
        __syncthreads();
    }
    if (t < B) blockSums[t] = (t == 0) ? 0 : sh[t - 1];   // exclusive
    if (t == B - 1) ptr[N] = sh[t];                        // total
}

__global__ __launch_bounds__(256) void k_scan_c(const int* __restrict__ cntI,
                                                const int* __restrict__ blockSums,
                                                int* __restrict__ ptr, int N) {
    __shared__ int th[256];
    int b = blockIdx.x, t = threadIdx.x;
    int base = b * 1024 + t * 4;
    int v[4]; int s = 0;
    #pragma unroll
    for (int i = 0; i < 4; ++i) {
        int idx = base + i;
        v[i] = (idx < N) ? cntI[idx] : 0;
        s += v[i];
    }
    th[t] = s;
    __syncthreads();
    for (int off = 1; off < 256; off <<= 1) {
        int xv = (t >= off) ? th[t - off] : 0;
        __syncthreads();
        th[t] += xv;
        __syncthreads();
    }
    int pre = ((t == 0) ? 0 : th[t - 1]) + blockSums[b];
    #pragma unroll
    for (int i = 0; i < 4; ++i) {
        int idx = base + i;
        if (idx < N) ptr[idx] = pre;
        pre += v[i];
    }
}

// ---------- CSR build ----------

__global__ void k_scatter(const int* __restrict__ row, const int* __restrict__ col,
                          const float* __restrict__ attr, const float* __restrict__ dinv,
                          const int* __restrict__ colptr,
                          int* __restrict__ rank,
                          unsigned* __restrict__ csrX, int E) {
    int e = blockIdx.x * blockDim.x + threadIdx.x;
    if (e < E) {
        int r = row[e], c = col[e];
        int pos = colptr[c] + rank[e];
        float nrm = dinv[r] * attr[e] * dinv[c];
        unsigned short nb = __half_as_ushort(__float2half(nrm));   // sign bit = 0
        csrX[pos] = (unsigned)r | ((unsigned)nb << 17);
        rank[e] = pos;
    }
}

// ---------- colof fill: colof[colptr[n]..colptr[n+1]) = n (contiguous runs) ----------

__global__ __launch_bounds__(256) void k_fill(const int* __restrict__ colptr,
                                              int* __restrict__ colof, int N) {
    int lane = threadIdx.x & 63;
    int wid  = (blockIdx.x * blockDim.x + threadIdx.x) >> 6;
    int nw   = (gridDim.x * blockDim.x) >> 6;
    for (int n = wid; n < N; n += nw) {
        int beg = colptr[n], end = colptr[n + 1];
        for (int p = beg + lane; p < end; p += 64) colof[p] = n;
    }
}

// ---------- encoder folding: g1 = x * (w_enc@W1) + b_enc@W1 (rank-1) ----------

__global__ void k_fold(const float* __restrict__ w_enc, const float* __restrict__ b_enc,
                       const float* __restrict__ W1,
                       float* __restrict__ we1, float* __restrict__ be1) {
    int j = threadIdx.x;
    if (j < L) {
        float a = 0.f, b = 0.f;
        for (int f = 0; f < L; ++f) {
            float wv = W1[f * L + j];
            a += w_enc[f] * wv;
            b += b_enc[f] * wv;
        }
        we1[j] = a; be1[j] = b;
    }
}

__global__ void k_encode(const float* __restrict__ x, const float* __restrict__ we1,
                         const float* __restrict__ be1, __half* __restrict__ g, int N) {
    int idx = blockIdx.x * blockDim.x + threadIdx.x;
    if (idx < N * L) {
        int n = idx >> 6, f = idx & 63;
        g[idx] = __float2half(x[n] * we1[f] + be1[f]);
    }
}

// ---------- gather-aggregate: h_out = relu(rcnt * sum(norm*g[row]) + b) ----------
// R7/R12-proven structure, R13 best config. R13 (occupancy bump: null) and
// R14 (2-stage pipeline: REGRESSED) establish this kernel is bound by random
// gather L3/request throughput (~4.5 TB/s effective), not per-wave latency --
// this simple form is its floor.

__global__ __launch_bounds__(256, 8) void k_agg(const uint4* __restrict__ h4,
        __half* __restrict__ h_out, const float* __restrict__ bias,
        const int* __restrict__ colptr, const unsigned* __restrict__ csrX,
        const float* __restrict__ rcnt, int N) {
    int lane = threadIdx.x & 63;
    int grp  = lane >> 3;              // 8 groups of 8 lanes
    int sub  = lane & 7;               // 16B slice index within a row
    int wid  = (blockIdx.x * blockDim.x + threadIdx.x) >> 6;
    int nw   = (gridDim.x * blockDim.x) >> 6;

    float bl8[8];                      // bias for features 8*sub..8*sub+7
    #pragma unroll
    for (int i = 0; i < 8; ++i) bl8[i] = bias[8 * sub + i];

    int beg = 0, end = 0; unsigned mw = 0;
    if (wid < N) {
        beg = colptr[wid];
        end = colptr[wid + 1];
        if (beg + lane < end) mw = csrX[beg + lane];   // inactive lanes: 0 -> +0
    }

    for (int n = wid; n < N; n += nw) {
        int n2 = n + nw;
        int beg2 = 0, end2 = 0;
        if (n2 < N) { beg2 = colptr[n2]; end2 = colptr[n2 + 1]; }
        float rcv = rcnt[n];

        float va[8];
        #pragma unroll
        for (int i = 0; i < 8; ++i) va[i] = 0.f;

        auto PROC = [&](unsigned mwv, int mm) {
            int kmax = (mm + 7) >> 3;
            int k = 0;
            while (k < kmax) {
                int rem = kmax - k;    // wave-uniform branch
                if (rem >= 4) {
                    unsigned x0, x1, x2, x3; uint4 q0, q1, q2, q3;
                    GLOAD(x0, q0, k) GLOAD(x1, q1, k + 1)
                    GLOAD(x2, q2, k + 2) GLOAD(x3, q3, k + 3)
                    FMA8(va, q0, x0) FMA8(va, q1, x1)
                    FMA8(va, q2, x2) FMA8(va, q3, x3)
                    k += 4;
                } else if (rem == 3) {
                    unsigned x0, x1, x2; uint4 q0, q1, q2;
                    GLOAD(x0, q0, k) GLOAD(x1, q1, k + 1) GLOAD(x2, q2, k + 2)
                    FMA8(va, q0, x0) FMA8(va, q1, x1) FMA8(va, q2, x2)
                    k += 3;
                } else if (rem == 2) {
                    unsigned x0, x1; uint4 q0, q1;
                    GLOAD(x0, q0, k) GLOAD(x1, q1, k + 1)
                    FMA8(va, q0, x0) FMA8(va, q1, x1)
                    k += 2;
                } else {
                    unsigned x0; uint4 q0;
                    GLOAD(x0, q0, k)
                    FMA8(va, q0, x0)
                    k += 1;
                }
            }
        };

        int m = end - beg; if (m > 64) m = 64;
        PROC(mw, m);
        for (int base = beg + 64; base < end; base += 64) {   // rare (deg>64)
            int mm = end - base; if (mm > 64) mm = 64;
            unsigned mwc = 0;
            if (lane < mm) mwc = csrX[base + lane];
            PROC(mwc, mm);
        }

        unsigned mw2 = 0;
        if (n2 < N && beg2 + lane < end2) mw2 = csrX[beg2 + lane];

        float s[8];
        #pragma unroll
        for (int i = 0; i < 8; ++i) {
            float v = va[i];
            v += __shfl_xor(v, 8);
            v += __shfl_xor(v, 16);
            v += __shfl_xor(v, 32);
            s[i] = v;
        }
        if (lane < 8) {                // sub == lane: features 8*lane..8*lane+7
            unsigned u[4];
            #pragma unroll
            for (int i = 0; i < 4; ++i) {
                float oa = fmaxf(s[2 * i]     * rcv + bl8[2 * i],     0.f);
                float ob = fmaxf(s[2 * i + 1] * rcv + bl8[2 * i + 1], 0.f);
                u[i] = (unsigned)__half_as_ushort(__float2half(oa))
                     | ((unsigned)__half_as_ushort(__float2half(ob)) << 16);
            }
            uint4 st; st.x = u[0]; st.y = u[1]; st.z = u[2]; st.w = u[3];
            ((uint4*)h_out)[(size_t)n * 8 + lane] = st;
        }

        beg = beg2; end = end2; mw = mw2;
    }
}

// ---------- dense transform g = h @ W via MFMA (split-fp16 W: full f32 accuracy) ----------

__global__ __launch_bounds__(256) void k_gx(const __half* __restrict__ h,
        const float* __restrict__ W, __half* __restrict__ g, int N) {
    int lane = threadIdx.x & 63;
    int wid  = (blockIdx.x * blockDim.x + threadIdx.x) >> 6;
    int nw   = (gridDim.x * blockDim.x) >> 6;
    int r16  = lane & 15;
    int q4   = lane >> 4;

    f16x8 bh[4][2], bl[4][2];          // B frags: [col-tile][k-step]
    #pragma unroll
    for (int t = 0; t < 4; ++t)
        #pragma unroll
        for (int ks = 0; ks < 2; ++ks)
            #pragma unroll
            for (int i = 0; i < 8; ++i) {
                int k = ks * 32 + q4 * 8 + i;
                float wv = W[k * L + t * 16 + r16];
                _Float16 hi = (_Float16)wv;
                bh[t][ks][i] = hi;
                bl[t][ks][i] = (_Float16)(wv - (float)hi);
            }

    int tiles = (N + 15) >> 4;
    for (int tt = wid; tt < tiles; tt += nw) {
        int n0 = tt << 4;
        int row = n0 + r16; if (row >= N) row = N - 1;
        f16x8 a0 = *(const f16x8*)(h + (size_t)row * L + q4 * 8);
        f16x8 a1 = *(const f16x8*)(h + (size_t)row * L + 32 + q4 * 8);
        #pragma unroll
        for (int t = 0; t < 4; ++t) {
            f32x4 acc = {0.f, 0.f, 0.f, 0.f};
            acc = __builtin_amdgcn_mfma_f32_16x16x32_f16(a0, bl[t][0], acc, 0, 0, 0);
            acc = __builtin_amdgcn_mfma_f32_16x16x32_f16(a1, bl[t][1], acc, 0, 0, 0);
            acc = __builtin_amdgcn_mfma_f32_16x16x32_f16(a0, bh[t][0], acc, 0, 0, 0);
            acc = __builtin_amdgcn_mfma_f32_16x16x32_f16(a1, bh[t][1], acc, 0, 0, 0);
            #pragma unroll
            for (int r = 0; r < 4; ++r) {
                int node = n0 + q4 * 4 + r;
                if (node < N)
                    g[(size_t)node * L + t * 16 + r16] = __float2half(acc[r]);
            }
        }
    }
}

// ---------- decoder node matvecs via MFMA: U = h@W1[:64]+b1, V = h@W1[64:] ----------

__global__ __launch_bounds__(256) void k_mv2(const __half* __restrict__ h,
        const float* __restrict__ W1, const float* __restrict__ b1,
        __half* __restrict__ U, __half* __restrict__ V, int N) {
    int lane = threadIdx.x & 63;
    int wid  = (blockIdx.x * blockDim.x + threadIdx.x) >> 6;
    int nw   = (gridDim.x * blockDim.x) >> 6;
    int r16  = lane & 15;
    int q4   = lane >> 4;
    int tiles = (N + 15) >> 4;

    for (int phase = 0; phase < 2; ++phase) {
        const float* W = W1 + (size_t)phase * L * L;   // Wu rows 0..63, Wv rows 64..127
        __half* O = phase ? V : U;
        f16x8 bh[4][2], bl[4][2];
        float bv[4];
        #pragma unroll
        for (int t = 0; t < 4; ++t) {
            bv[t] = phase ? 0.f : b1[t * 16 + r16];
            #pragma unroll
            for (int ks = 0; ks < 2; ++ks)
                #pragma unroll
                for (int i = 0; i < 8; ++i) {
                    int k = ks * 32 + q4 * 8 + i;
                    float wv = W[k * L + t * 16 + r16];
                    _Float16 hi = (_Float16)wv;
                    bh[t][ks][i] = hi;
                    bl[t][ks][i] = (_Float16)(wv - (float)hi);
                }
        }
        for (int tt = wid; tt < tiles; tt += nw) {
            int n0 = tt << 4;
            int row = n0 + r16; if (row >= N) row = N - 1;
            f16x8 a0 = *(const f16x8*)(h + (size_t)row * L + q4 * 8);
            f16x8 a1 = *(const f16x8*)(h + (size_t)row * L + 32 + q4 * 8);
            #pragma unroll
            for (int t = 0; t < 4; ++t) {
                f32x4 acc = {0.f, 0.f, 0.f, 0.f};
                acc = __builtin_amdgcn_mfma_f32_16x16x32_f16(a0, bl[t][0], acc, 0, 0, 0);
                acc = __builtin_amdgcn_mfma_f32_16x16x32_f16(a1, bl[t][1], acc, 0, 0, 0);
                acc = __builtin_amdgcn_mfma_f32_16x16x32_f16(a0, bh[t][0], acc, 0, 0, 0);
                acc = __builtin_amdgcn_mfma_f32_16x16x32_f16(a1, bh[t][1], acc, 0, 0, 0);
                #pragma unroll
                for (int r = 0; r < 4; ++r) {
                    int node = n0 + q4 * 4 + r;
                    if (node < N)
                        O[(size_t)node * L + t * 16 + r16] = __float2half(acc[r] + bv[t]);
                }
            }
        }
    }
}

// ---------- decoder edge pass: EDGE-PARALLEL, 8 lanes per CSR position ----------

__global__ __launch_bounds__(256, 8) void k_edge(const __half* __restrict__ U,
        const __half* __restrict__ V, const float* __restrict__ w2,
        const float* __restrict__ b2, const unsigned* __restrict__ csrX,
        const int* __restrict__ colof, float* __restrict__ tmp, int E) {
    int sub = threadIdx.x & 7;
    float w2f[8];
    #pragma unroll
    for (int i = 0; i < 8; ++i) w2f[i] = w2[8 * sub + i];
    float b2v = b2[0];
    int tid = blockIdx.x * blockDim.x + threadIdx.x;
    int np  = (gridDim.x * blockDim.x) >> 3;
    for (int p = tid >> 3; p < E; p += np) {
        unsigned md = csrX[p];
        int r = (int)(md & 0x1FFFFu);
        int n = colof[p];
        uint4 uq = ((const uint4*)(U + (size_t)r * L))[sub];
        uint4 vq = ((const uint4*)(V + (size_t)n * L))[sub];
        float p0 = 0.f, p1 = 0.f;
        #define DOT2X(uw_, vw_, B) { unsigned t_; \
            PKADDRELU(t_, (uw_), (vw_)); \
            FMAMIX_LO(p0, t_, w2f[B]); FMAMIX_HI(p1, t_, w2f[(B) + 1]); }
        DOT2X(uq.x, vq.x, 0) DOT2X(uq.y, vq.y, 2)
        DOT2X(uq.z, vq.z, 4) DOT2X(uq.w, vq.w, 6)
        #undef DOT2X
        float pd = p0 + p1;
        pd += __shfl_xor(pd, 1);
        pd += __shfl_xor(pd, 2);
        pd += __shfl_xor(pd, 4);
        if (sub == 0) tmp[p] = pd + b2v;
    }
}

// ---------- permute CSR-ordered results back to edge order (+ softplus) ----------

__global__ void k_perm(const int* __restrict__ epos, const float* __restrict__ tmp,
                       const int* __restrict__ erow, const int* __restrict__ ecol,
                       float* __restrict__ out, int E) {
    int e = blockIdx.x * blockDim.x + threadIdx.x;
    if (e < E) {
        float val = tmp[epos[e]];
        if (erow[e] == ecol[e])
            val = fmaxf(val, 0.f) + log1pf(expf(-fabsf(val)));
        out[e] = val;
    }
}

// ---------- launch ----------

extern "C" void kernel_launch(void* const* d_in, const int* in_sizes, int n_in,
                              void* d_out, int out_size, void* d_ws, size_t ws_size,
                              hipStream_t stream) {
    const float* x     = (const float*)d_in[0];
    const float* attr  = (const float*)d_in[1];
    const float* w_enc = (const float*)d_in[2];
    const float* b_enc = (const float*)d_in[3];
    const float* c1w   = (const float*)d_in[4];
    const float* c1b   = (const float*)d_in[5];
    const float* c2w   = (const float*)d_in[6];
    const float* c2b   = (const float*)d_in[7];
    const float* dw1   = (const float*)d_in[8];
    const float* db1   = (const float*)d_in[9];
    const float* dw2   = (const float*)d_in[10];
    const float* db2   = (const float*)d_in[11];
    const int*   erow  = (const int*)d_in[12];
    const int*   ecol  = (const int*)d_in[13];
    int N = in_sizes[0];
    int E = in_sizes[1];
    float* out = (float*)d_out;

    char* w = (char*)d_ws;
    auto alloc = [&](size_t bytes) {
        char* p = w; w += (bytes + 255) & ~(size_t)255; return p;
    };
    unsigned* degcnt = (unsigned*)alloc((size_t)N * 4);  // zeroed
    size_t zbytes = (size_t)(w - (char*)d_ws);
    float* dinv   = (float*)alloc((size_t)N * 4);
    int*   cntI   = (int*)  alloc((size_t)N * 4);
    float* rcnt   = (float*)alloc((size_t)N * 4);
    int*   colptr = (int*)  alloc((size_t)(N + 1) * 4);
    int*   bsums  = (int*)  alloc(((size_t)(N + 1023) / 1024 + 1) * 4);
    float* we1    = (float*)alloc(L * 4);
    float* be1    = (float*)alloc(L * 4);
    int*   rank   = (int*)  alloc((size_t)E * 4);   // per-col rank, then abs CSR pos
    unsigned* csrX = (unsigned*)alloc((size_t)E * 4);
    int*   colof  = (int*)  alloc((size_t)E * 4);   // owning col per CSR position
    float* tmp    = (float*)alloc((size_t)E * 4);
    __half* hA    = (__half*)alloc((size_t)N * L * 2);   // fp16 h ping
    __half* hB    = (__half*)alloc((size_t)N * L * 2);   // fp16 h pong
    __half* hU    = (__half*)alloc((size_t)N * L * 2);   // decoder U; aliases g
    __half* hV    = (__half*)alloc((size_t)N * L * 2);   // decoder V (fp16)
    __half* gbuf  = hU;   // g buffer lives in hU until k_mv2 (which reads hB)
    (void)ws_size; (void)n_in; (void)out_size;

    (void)hipMemsetAsync(d_ws, 0, zbytes, stream);

    int eb = (E + 255) / 256;
    int nb = (N + 255) / 256;
    int B  = (N + 1023) / 1024;     // scan chunks
    k_hist<<<eb, 256, 0, stream>>>(ecol, attr, degcnt, rank, E);
    k_dinv<<<nb, 256, 0, stream>>>(degcnt, dinv, cntI, rcnt, N);
    k_scan_a<<<B, 256, 0, stream>>>(cntI, bsums, N);
    k_scan_b<<<1, 1024, 0, stream>>>(bsums, B, colptr, N);
    k_scan_c<<<B, 256, 0, stream>>>(cntI, bsums, colptr, N);
    k_scatter<<<eb, 256, 0, stream>>>(erow, ecol, attr, dinv, colptr, rank, csrX, E);
    k_fill<<<1024, 256, 0, stream>>>(colptr, colof, N);

    // encoder folded with conv1_0's W: g1 = x * (w_enc@W) + b_enc@W
    k_fold<<<1, 64, 0, stream>>>(w_enc, b_enc, c1w, we1, be1);
    k_encode<<<(N * L + 255) / 256, 256, 0, stream>>>(x, we1, be1, gbuf, N);

    // 6 conv layers: agg(g) -> h; then g = h @ W_next (except after the last)
    const float* Ws[6] = {c1w,             c2w,
                          c1w + L * L,     c2w + L * L,
                          c1w + 2 * L * L, c2w + 2 * L * L};
    const float* Bs[6] = {c1b,         c2b,
                          c1b + L,     c2b + L,
                          c1b + 2 * L, c2b + 2 * L};
    (void)Ws[0];   // folded into the encoder
    __half* outs[2] = {hA, hB};
    __half* hcur = nullptr;
    for (int j = 0; j < 6; ++j) {
        hcur = outs[j & 1];
        k_agg<<<2048, 256, 0, stream>>>((const uint4*)gbuf, hcur, Bs[j],
                                        colptr, csrX, rcnt, N);
        if (j < 5)
            k_gx<<<512, 256, 0, stream>>>(hcur, Ws[j + 1], gbuf, N);
    }
    // h_final in hcur (= hB). U -> hU (b1 folded), V -> hV
    k_mv2<<<512, 256, 0, stream>>>(hcur, dw1, db1, hU, hV, N);
    k_edge<<<2048, 256, 0, stream>>>(hU, hV, dw2, db2, csrX, colof, tmp, E);
    k_perm<<<eb, 256, 0, stream>>>(rank, tmp, erow, ecol, out, E);
}